// Round 12
// baseline (71.960 us; speedup 1.0000x reference)
//
#include <hip/hip_runtime.h>
#include <math.h>

#define NG      1024
#define IMG_H   128
#define IMG_W   128
#define NPIX    (IMG_H * IMG_W)
#define MIN_A   (1.0f / 255.0f)
#define LOG2E   1.4426950408889634f

// Record layout (per gaussian, sorted by z):
//  g0 = {mx, my, a2, b2}          a2 = -0.5*conicA*log2e, b2 = -conicB*log2e
//  g1 = {c2, op_eff, colR, colG}  c2 = -0.5*conicC*log2e
//  g2 = colB
//  g3 = {mx, my, dxm, dym}        exact AABB of the alpha>=1/255 level set
// G = exp2( min(a2*dx^2 + c2*dy^2 + b2*dx*dy, 0) )
//
// SINGLE DISPATCH producer-consumer:
//  blocks 0-15 prep 64 gaussians each -> fence -> atomicOr(flag, 1<<b).
//  all 256 blocks spin (tid0, acquire) until flag low 16 bits full, then
//  rasterize one 8x8 tile (r11's proven ballot-cull raster).
//  Deadlock-free: 256 blocks x 1024 thr, ~81KB LDS -> 1 block/CU, grid==CU
//  count -> all co-resident. Replays: flag already full (atomicOr idempotent)
//  -> no wait; concurrent record rewrites are byte-identical -> deterministic.
//  0xAA-poisoned flag (0xAAAAAAAA) has low bits != 0xFFFF -> first call spins
//  correctly; prep ORs in all 16 bits.

__global__ __launch_bounds__(1024) void gs_all(
    const float* __restrict__ pos, const float* __restrict__ cov,
    const float* __restrict__ col, const float* __restrict__ opa,
    const float* __restrict__ cm,
    float4* __restrict__ g0, float4* __restrict__ g1, float* __restrict__ g2,
    float4* __restrict__ g3, int* __restrict__ flag,
    float* __restrict__ out)
{
    // ---- prep-phase LDS (blocks 0-15 only) --------------------------------
    __shared__ float possh[NG * 3];      // 12 KB
    __shared__ float zsh[NG];            //  4 KB
    __shared__ float covsh[64 * 9];      // 2304 B
    __shared__ float colsh[64 * 3];      //  768 B
    __shared__ float opash[64];          //  256 B
    __shared__ int   prank[16][64];      //  4 KB
    // ---- raster-phase LDS (all blocks) ------------------------------------
    __shared__ float4 s0[NG];            // 16 KB
    __shared__ float4 s1[NG];            // 16 KB
    __shared__ float  s2[NG];            //  4 KB
    __shared__ float4 s3[NG];            // 16 KB
    __shared__ float4 part[16][64];      //  4 KB

    const int tid = threadIdx.x;
    const int b   = blockIdx.x;

    // ======================= PREP (blocks 0-15) ============================
    if (b < 16) {
        // coalesced staging: pos (768 f4) | cov (144 f4) | col (48) | opa (16)
        if      (tid < 768) ((float4*)possh)[tid]       = ((const float4*)pos)[tid];
        else if (tid < 912) ((float4*)covsh)[tid - 768] = ((const float4*)cov)[144 * b + tid - 768];
        else if (tid < 960) ((float4*)colsh)[tid - 912] = ((const float4*)col)[48 * b + tid - 912];
        else if (tid < 976) ((float4*)opash)[tid - 960] = ((const float4*)opa)[16 * b + tid - 960];
        __syncthreads();

        // all 1024 camera-z's, one per thread
        const float R20 = cm[8], R21 = cm[9], R22 = cm[10], T2 = cm[11];
        zsh[tid] = fmaf(R20, possh[3*tid],
                   fmaf(R21, possh[3*tid+1],
                   fmaf(R22, possh[3*tid+2], T2)));
        __syncthreads();

        // distributed stable rank: wave q counts z-chunk [64q,64q+64) for
        // gaussian g = tid&63 (16 b128 wave-uniform broadcasts per wave)
        {
            const int q = tid >> 6, g = tid & 63;
            const int i = (b << 6) + g;
            const float zi = zsh[i];
            const float4* z4 = (const float4*)zsh;
            int r = 0;
            #pragma unroll
            for (int j4 = q * 16; j4 < q * 16 + 16; ++j4) {
                const float4 v = z4[j4];
                const int j = 4 * j4;
                r += (v.x < zi || (v.x == zi && j + 0 < i)) ? 1 : 0;
                r += (v.y < zi || (v.y == zi && j + 1 < i)) ? 1 : 0;
                r += (v.z < zi || (v.z == zi && j + 2 < i)) ? 1 : 0;
                r += (v.w < zi || (v.w == zi && j + 3 < i)) ? 1 : 0;
            }
            prank[q][g] = r;
        }
        __syncthreads();

        // project + scatter (64 threads)
        if (tid < 64) {
            const int g = tid;
            const int i = (b << 6) + g;

            const float R00 = cm[0], R01 = cm[1], R02 = cm[2],  T0 = cm[3];
            const float R10 = cm[4], R11 = cm[5], R12 = cm[6],  T1 = cm[7];

            const float p0 = possh[3*i], p1 = possh[3*i+1], p2 = possh[3*i+2];
            const float x = R00*p0 + R01*p1 + R02*p2 + T0;
            const float y = R10*p0 + R11*p1 + R12*p2 + T1;
            const float z = zsh[i];

            const float focal = 110.85125168440814f;   // 0.5*128/tan(pi/6)
            const float zc = fmaxf(z, 1e-6f);
            const float mx = focal * x / zc + 0.5f * IMG_W;
            const float my = focal * y / zc + 0.5f * IMG_H;

            const float c00 = covsh[9*g+0], c01 = covsh[9*g+1], c02 = covsh[9*g+2];
            const float c10 = covsh[9*g+3], c11 = covsh[9*g+4], c12 = covsh[9*g+5];
            const float c20 = covsh[9*g+6], c21 = covsh[9*g+7], c22 = covsh[9*g+8];
            const float s00 = c00, s01 = 0.5f*(c01+c10), s02 = 0.5f*(c02+c20);
            const float s11 = c11, s12 = 0.5f*(c12+c21), s22 = c22;

            const float RS00 = R00*s00 + R01*s01 + R02*s02;
            const float RS01 = R00*s01 + R01*s11 + R02*s12;
            const float RS02 = R00*s02 + R01*s12 + R02*s22;
            const float RS10 = R10*s00 + R11*s01 + R12*s02;
            const float RS11 = R10*s01 + R11*s11 + R12*s12;
            const float RS12 = R10*s02 + R11*s12 + R12*s22;
            const float RS20 = R20*s00 + R21*s01 + R22*s02;
            const float RS21 = R20*s01 + R21*s11 + R22*s12;
            const float RS22 = R20*s02 + R21*s12 + R22*s22;
            const float CC00 = RS00*R00 + RS01*R01 + RS02*R02;
            const float CC01 = RS00*R10 + RS01*R11 + RS02*R12;
            const float CC02 = RS00*R20 + RS01*R21 + RS02*R22;
            const float CC11 = RS10*R10 + RS11*R11 + RS12*R12;
            const float CC12 = RS10*R20 + RS11*R21 + RS12*R22;
            const float CC20 = RS20*R00 + RS21*R01 + RS22*R02;
            const float CC21 = RS20*R10 + RS21*R11 + RS22*R12;
            const float CC22 = RS20*R20 + RS21*R21 + RS22*R22;

            const float j00 = focal / zc, j02 = -focal * x / (zc*zc);
            const float j11 = focal / zc, j12 = -focal * y / (zc*zc);

            const float v00 = CC00*j00 + CC02*j02;
            const float v02 = CC20*j00 + CC22*j02;
            const float v10 = CC01*j11 + CC02*j12;
            const float v11 = CC11*j11 + CC12*j12;
            const float v12 = CC21*j11 + CC22*j12;

            const float a  = j00*v00 + j02*v02 + 0.3f;
            const float bq = j00*v10 + j02*v12;
            const float cQ = j11*v11 + j12*v12 + 0.3f;

            const float det = a*cQ - bq*bq;
            const float det_safe = (det > 0.f) ? det : 1.f;
            const float conA =  cQ / det_safe;
            const float conB = -bq / det_safe;
            const float conC =  a  / det_safe;

            const bool  valid  = (z > 0.2f) && (det > 0.f);
            const float op_eff = valid ? opash[g] : 0.f;

            float dxm, dym;
            if (op_eff * 255.f > 1.f) {
                const float sN = logf(255.f * op_eff);
                dxm = sqrtf(2.f * sN * a)  * 1.001f + 0.06f;  // conservative
                dym = sqrtf(2.f * sN * cQ) * 1.001f + 0.06f;
            } else {
                dxm = -1e30f; dym = -1e30f;                   // never visible
            }

            const int rank = prank[0][g]  + prank[1][g]  + prank[2][g]  + prank[3][g]
                           + prank[4][g]  + prank[5][g]  + prank[6][g]  + prank[7][g]
                           + prank[8][g]  + prank[9][g]  + prank[10][g] + prank[11][g]
                           + prank[12][g] + prank[13][g] + prank[14][g] + prank[15][g];

            g0[rank] = make_float4(mx, my, -0.5f*conA*LOG2E, -conB*LOG2E);
            g1[rank] = make_float4(-0.5f*conC*LOG2E, op_eff, colsh[3*g], colsh[3*g+1]);
            g2[rank] = colsh[3*g+2];
            g3[rank] = make_float4(mx, my, dxm, dym);
            __threadfence();                 // writer-side device-scope fence
        }
        __syncthreads();
        if (tid == 0)
            __hip_atomic_fetch_or(flag, 1 << b, __ATOMIC_RELEASE,
                                  __HIP_MEMORY_SCOPE_AGENT);
    }

    // ===================== WAIT FOR ALL RECORDS ============================
    if (tid == 0) {
        while ((__hip_atomic_load(flag, __ATOMIC_ACQUIRE,
                                  __HIP_MEMORY_SCOPE_AGENT) & 0xFFFF) != 0xFFFF)
            __builtin_amdgcn_s_sleep(2);
    }
    __syncthreads();
    __threadfence();                         // reader-side fence

    // ======================= RASTER (all 256 blocks) =======================
    s0[tid] = g0[tid];
    s1[tid] = g1[tid];
    s2[tid] = g2[tid];
    s3[tid] = g3[tid];
    __syncthreads();

    const int w    = tid >> 6;               // wave = chunk 0..15
    const int lane = tid & 63;               // pixel in 8x8 tile / cull lane
    const float tx0 = (float)((b & 15) << 3);
    const float ty0 = (float)((b >> 4) << 3);

    const float pxf = tx0 + (float)(lane & 7) + 0.5f;
    const float pyf = ty0 + (float)(lane >> 3) + 0.5f;
    const float txl = tx0 + 0.5f, txh = tx0 + 7.5f;
    const float tyl = ty0 + 0.5f, tyh = ty0 + 7.5f;

    const int base = w * 64;

    // lane-parallel AABB cull -> uniform 64-bit mask
    const float4 cl = s3[base + lane];
    const bool hitc = (cl.x - cl.z <= txh) && (cl.x + cl.z >= txl)
                   && (cl.y - cl.w <= tyh) && (cl.y + cl.w >= tyl);
    unsigned long long m = __ballot(hitc);

    float T = 1.f, cr = 0.f, cg = 0.f, cb = 0.f;

    while (m) {                              // ascending bits == z order
        const int i = __builtin_ctzll(m);
        m &= m - 1;
        const float4 A = s0[base + i];       // wave-uniform broadcasts
        const float4 B = s1[base + i];
        const float  C = s2[base + i];
        const float dx = pxf - A.x;
        const float dy = pyf - A.y;
        const float pw = fminf(A.z*dx*dx + B.x*dy*dy + A.w*(dx*dy), 0.f);
        const float G = __builtin_amdgcn_exp2f(pw);
        float alpha = fminf(B.y * G, 0.99f);
        alpha = (alpha >= MIN_A) ? alpha : 0.f;
        const float wT = alpha * T;
        cr = fmaf(wT, B.z, cr);
        cg = fmaf(wT, B.w, cg);
        cb = fmaf(wT, C,   cb);
        T *= (1.f - alpha);
    }

    part[w][lane] = make_float4(cr, cg, cb, T);
    __syncthreads();

    if (tid < 64) {                          // per-pixel 16-chunk scan
        float Ts = 1.f, r = 0.f, g = 0.f, bl = 0.f;
        #pragma unroll
        for (int k = 0; k < 16; ++k) {
            const float4 v = part[k][tid];
            r  = fmaf(Ts, v.x, r);
            g  = fmaf(Ts, v.y, g);
            bl = fmaf(Ts, v.z, bl);
            Ts *= v.w;
        }
        const int px = (int)tx0 + (tid & 7);
        const int py = (int)ty0 + (tid >> 3);
        float* o = out + 3 * (py * IMG_W + px);
        o[0] = r; o[1] = g; o[2] = bl;
    }
}

// ---------------------------------------------------------------------------
extern "C" void kernel_launch(void* const* d_in, const int* in_sizes, int n_in,
                              void* d_out, int out_size, void* d_ws, size_t ws_size,
                              hipStream_t stream) {
    const float* pos = (const float*)d_in[0];
    const float* cov = (const float*)d_in[1];
    const float* col = (const float*)d_in[2];
    const float* opa = (const float*)d_in[3];
    const float* cm  = (const float*)d_in[4];

    char* ws = (char*)d_ws;
    float4* g0 = (float4*)(ws);                 // 16384 B
    float4* g1 = (float4*)(ws + 16384);         // 16384 B
    float*  g2 = (float*) (ws + 32768);         //  4096 B
    float4* g3 = (float4*)(ws + 36864);         // 16384 B
    int*    fl = (int*)   (ws + 53248);         //     4 B completion bitmask

    gs_all<<<256, 1024, 0, stream>>>(pos, cov, col, opa, cm,
                                     g0, g1, g2, g3, fl, (float*)d_out);
}

// Round 13
// 14.026 us; speedup vs baseline: 5.1306x; 5.1306x over previous
//
#include <hip/hip_runtime.h>
#include <math.h>

#define NG      1024
#define IMG_H   128
#define IMG_W   128
#define NPIX    (IMG_H * IMG_W)
#define MIN_A   (1.0f / 255.0f)
#define LOG2E   1.4426950408889634f

// Record layout (per gaussian, sorted by z):
//  g0 = {mx, my, a2, b2}          a2 = -0.5*conicA*log2e, b2 = -conicB*log2e
//  g1 = {c2, op_eff, colR, colG}  c2 = -0.5*conicC*log2e
//  g2 = colB
//  g3 = {mx, my, dxm, dym}        exact AABB of the alpha>=1/255 level set
// G = exp2( min(a2*dx^2 + c2*dy^2 + b2*dx*dy, 0) )

// ---------------------------------------------------------------------------
// Kernel 1: fused project + stable rank-sort + scatter. 16 blocks x 1024.
// One coalesced staging burst; z one-per-thread; rank distributed 16-way
// (wave q counts z-chunk [64q,64q+64) for gaussian g=tid&63 via 16 broadcast
// ds_read_b128); wave 0 projects from LDS and scatters by rank.
// ---------------------------------------------------------------------------
__global__ __launch_bounds__(1024) void gs_prep(
    const float* __restrict__ pos, const float* __restrict__ cov,
    const float* __restrict__ col, const float* __restrict__ opa,
    const float* __restrict__ cm,
    float4* __restrict__ g0, float4* __restrict__ g1, float* __restrict__ g2,
    float4* __restrict__ g3)
{
    __shared__ float possh[NG * 3];      // 12 KB
    __shared__ float zsh[NG];            //  4 KB
    __shared__ float covsh[64 * 9];      // 2304 B (this block's 64 gaussians)
    __shared__ float colsh[64 * 3];      //  768 B
    __shared__ float opash[64];          //  256 B
    __shared__ int   prank[16][64];      //  4 KB

    const int tid = threadIdx.x;
    const int b   = blockIdx.x;          // 16 blocks, 64 gaussians each

    // ---- coalesced staging: pos(768 f4) | cov(144 f4) | col(48) | opa(16) --
    if      (tid < 768) ((float4*)possh)[tid]       = ((const float4*)pos)[tid];
    else if (tid < 912) ((float4*)covsh)[tid - 768] = ((const float4*)cov)[144 * b + tid - 768];
    else if (tid < 960) ((float4*)colsh)[tid - 912] = ((const float4*)col)[48 * b + tid - 912];
    else if (tid < 976) ((float4*)opash)[tid - 960] = ((const float4*)opa)[16 * b + tid - 960];
    __syncthreads();

    // ---- all 1024 camera-z's, one per thread ------------------------------
    const float R20 = cm[8], R21 = cm[9], R22 = cm[10], T2 = cm[11];
    zsh[tid] = fmaf(R20, possh[3*tid],
               fmaf(R21, possh[3*tid+1],
               fmaf(R22, possh[3*tid+2], T2)));
    __syncthreads();

    // ---- distributed stable rank (16-way) ---------------------------------
    {
        const int q = tid >> 6, g = tid & 63;
        const int i = (b << 6) + g;
        const float zi = zsh[i];
        const float4* z4 = (const float4*)zsh;
        int r = 0;
        #pragma unroll
        for (int j4 = q * 16; j4 < q * 16 + 16; ++j4) {
            const float4 v = z4[j4];     // wave-uniform broadcast
            const int j = 4 * j4;
            r += (v.x < zi || (v.x == zi && j + 0 < i)) ? 1 : 0;
            r += (v.y < zi || (v.y == zi && j + 1 < i)) ? 1 : 0;
            r += (v.z < zi || (v.z == zi && j + 2 < i)) ? 1 : 0;
            r += (v.w < zi || (v.w == zi && j + 3 < i)) ? 1 : 0;
        }
        prank[q][g] = r;
    }
    __syncthreads();

    // ---- wave 0: project from LDS + scatter by rank -----------------------
    if (tid < 64) {
        const int g = tid;
        const int i = (b << 6) + g;

        const float R00 = cm[0], R01 = cm[1], R02 = cm[2],  T0 = cm[3];
        const float R10 = cm[4], R11 = cm[5], R12 = cm[6],  T1 = cm[7];

        const float p0 = possh[3*i], p1 = possh[3*i+1], p2 = possh[3*i+2];
        const float x = R00*p0 + R01*p1 + R02*p2 + T0;
        const float y = R10*p0 + R11*p1 + R12*p2 + T1;
        const float z = zsh[i];

        const float focal = 110.85125168440814f;   // 0.5*128/tan(pi/6)
        const float zc = fmaxf(z, 1e-6f);
        const float mx = focal * x / zc + 0.5f * IMG_W;
        const float my = focal * y / zc + 0.5f * IMG_H;

        const float c00 = covsh[9*g+0], c01 = covsh[9*g+1], c02 = covsh[9*g+2];
        const float c10 = covsh[9*g+3], c11 = covsh[9*g+4], c12 = covsh[9*g+5];
        const float c20 = covsh[9*g+6], c21 = covsh[9*g+7], c22 = covsh[9*g+8];
        const float s00 = c00, s01 = 0.5f*(c01+c10), s02 = 0.5f*(c02+c20);
        const float s11 = c11, s12 = 0.5f*(c12+c21), s22 = c22;

        const float RS00 = R00*s00 + R01*s01 + R02*s02;
        const float RS01 = R00*s01 + R01*s11 + R02*s12;
        const float RS02 = R00*s02 + R01*s12 + R02*s22;
        const float RS10 = R10*s00 + R11*s01 + R12*s02;
        const float RS11 = R10*s01 + R11*s11 + R12*s12;
        const float RS12 = R10*s02 + R11*s12 + R12*s22;
        const float RS20 = R20*s00 + R21*s01 + R22*s02;
        const float RS21 = R20*s01 + R21*s11 + R22*s12;
        const float RS22 = R20*s02 + R21*s12 + R22*s22;
        const float CC00 = RS00*R00 + RS01*R01 + RS02*R02;
        const float CC01 = RS00*R10 + RS01*R11 + RS02*R12;
        const float CC02 = RS00*R20 + RS01*R21 + RS02*R22;
        const float CC11 = RS10*R10 + RS11*R11 + RS12*R12;
        const float CC12 = RS10*R20 + RS11*R21 + RS12*R22;
        const float CC20 = RS20*R00 + RS21*R01 + RS22*R02;
        const float CC21 = RS20*R10 + RS21*R11 + RS22*R12;
        const float CC22 = RS20*R20 + RS21*R21 + RS22*R22;

        const float j00 = focal / zc, j02 = -focal * x / (zc*zc);
        const float j11 = focal / zc, j12 = -focal * y / (zc*zc);

        const float v00 = CC00*j00 + CC02*j02;
        const float v02 = CC20*j00 + CC22*j02;
        const float v10 = CC01*j11 + CC02*j12;
        const float v11 = CC11*j11 + CC12*j12;
        const float v12 = CC21*j11 + CC22*j12;

        const float a  = j00*v00 + j02*v02 + 0.3f;
        const float bq = j00*v10 + j02*v12;
        const float cQ = j11*v11 + j12*v12 + 0.3f;

        const float det = a*cQ - bq*bq;
        const float det_safe = (det > 0.f) ? det : 1.f;
        const float conA =  cQ / det_safe;
        const float conB = -bq / det_safe;
        const float conC =  a  / det_safe;

        const bool  valid  = (z > 0.2f) && (det > 0.f);
        const float op_eff = valid ? opash[g] : 0.f;

        float dxm, dym;
        if (op_eff * 255.f > 1.f) {
            const float sN = logf(255.f * op_eff);
            dxm = sqrtf(2.f * sN * a)  * 1.001f + 0.06f;   // conservative outward
            dym = sqrtf(2.f * sN * cQ) * 1.001f + 0.06f;
        } else {
            dxm = -1e30f; dym = -1e30f;                    // never visible
        }

        const int rank = prank[0][g]  + prank[1][g]  + prank[2][g]  + prank[3][g]
                       + prank[4][g]  + prank[5][g]  + prank[6][g]  + prank[7][g]
                       + prank[8][g]  + prank[9][g]  + prank[10][g] + prank[11][g]
                       + prank[12][g] + prank[13][g] + prank[14][g] + prank[15][g];

        g0[rank] = make_float4(mx, my, -0.5f*conA*LOG2E, -conB*LOG2E);
        g1[rank] = make_float4(-0.5f*conC*LOG2E, op_eff, colsh[3*g], colsh[3*g+1]);
        g2[rank] = colsh[3*g+2];
        g3[rank] = make_float4(mx, my, dxm, dym);
    }
}

// ---------------------------------------------------------------------------
// Kernel 2: LDS-resident tile raster, register-cull, fused combine.
// 256 blocks x 1024 threads. Block = one 8x8 tile; wave w owns sorted chunk
// [64w, 64w+64). The cull record g3[tid] is loaded coalesced into a REGISTER:
// wave w's lanes hold exactly its chunk -> AABB test + __ballot gives the
// wave's hit mask with no s3 LDS at all (LDS 52->40 KB, fewer staging ops).
// Composite reads s0/s1/s2 via wave-uniform broadcasts, ascending bit order
// == z order. 16 partials/pixel in LDS; 16-step scan fuses the combine.
// ---------------------------------------------------------------------------
__global__ __launch_bounds__(1024) void gs_raster_tile(
    const float4* __restrict__ g0, const float4* __restrict__ g1,
    const float*  __restrict__ g2, const float4* __restrict__ g3,
    float* __restrict__ out)
{
    __shared__ float4 s0[NG];            // 16 KB
    __shared__ float4 s1[NG];            // 16 KB
    __shared__ float  s2[NG];            //  4 KB
    __shared__ float4 part[16][64];      //  4 KB [chunk][pixel]

    const int tid = threadIdx.x;
    const float4 cl = g3[tid];           // coalesced; wave w lane l = gaussian 64w+l
    s0[tid] = g0[tid];
    s1[tid] = g1[tid];
    s2[tid] = g2[tid];

    const int w    = tid >> 6;           // wave = chunk 0..15
    const int lane = tid & 63;           // pixel in 8x8 tile / cull lane
    const int tile = blockIdx.x;         // 16x16 tiles
    const float tx0 = (float)((tile & 15) << 3);
    const float ty0 = (float)((tile >> 4) << 3);

    const float pxf = tx0 + (float)(lane & 7) + 0.5f;
    const float pyf = ty0 + (float)(lane >> 3) + 0.5f;
    const float txl = tx0 + 0.5f, txh = tx0 + 7.5f;
    const float tyl = ty0 + 0.5f, tyh = ty0 + 7.5f;

    // register cull -> uniform 64-bit mask (no LDS dependency)
    const bool hit = (cl.x - cl.z <= txh) && (cl.x + cl.z >= txl)
                  && (cl.y - cl.w <= tyh) && (cl.y + cl.w >= tyl);
    unsigned long long m = __ballot(hit);

    __syncthreads();                     // s0/s1/s2 ready

    const int base = w * 64;
    float T = 1.f, cr = 0.f, cg = 0.f, cb = 0.f;

    while (m) {                          // ascending bit order == z order
        const int i = __builtin_ctzll(m);
        m &= m - 1;
        const float4 A = s0[base + i];   // wave-uniform broadcasts
        const float4 B = s1[base + i];
        const float  C = s2[base + i];
        const float dx = pxf - A.x;
        const float dy = pyf - A.y;
        const float pw = fminf(A.z*dx*dx + B.x*dy*dy + A.w*(dx*dy), 0.f);
        const float G = __builtin_amdgcn_exp2f(pw);
        float alpha = fminf(B.y * G, 0.99f);
        alpha = (alpha >= MIN_A) ? alpha : 0.f;
        const float wT = alpha * T;
        cr = fmaf(wT, B.z, cr);
        cg = fmaf(wT, B.w, cg);
        cb = fmaf(wT, C,   cb);
        T *= (1.f - alpha);
    }

    part[w][lane] = make_float4(cr, cg, cb, T);
    __syncthreads();

    if (tid < 64) {                      // one thread per pixel: 16-chunk scan
        float Ts = 1.f, r = 0.f, g = 0.f, b = 0.f;
        #pragma unroll
        for (int k = 0; k < 16; ++k) {
            const float4 v = part[k][tid];
            r = fmaf(Ts, v.x, r);
            g = fmaf(Ts, v.y, g);
            b = fmaf(Ts, v.z, b);
            Ts *= v.w;
        }
        const int px = (int)tx0 + (tid & 7);
        const int py = (int)ty0 + (tid >> 3);
        float* o = out + 3 * (py * IMG_W + px);
        o[0] = r; o[1] = g; o[2] = b;
    }
}

// ---------------------------------------------------------------------------
extern "C" void kernel_launch(void* const* d_in, const int* in_sizes, int n_in,
                              void* d_out, int out_size, void* d_ws, size_t ws_size,
                              hipStream_t stream) {
    const float* pos = (const float*)d_in[0];
    const float* cov = (const float*)d_in[1];
    const float* col = (const float*)d_in[2];
    const float* opa = (const float*)d_in[3];
    const float* cm  = (const float*)d_in[4];

    char* ws = (char*)d_ws;
    float4* g0 = (float4*)(ws);                 // 16384 B
    float4* g1 = (float4*)(ws + 16384);         // 16384 B
    float*  g2 = (float*) (ws + 32768);         //  4096 B
    float4* g3 = (float4*)(ws + 36864);         // 16384 B

    gs_prep<<<16, 1024, 0, stream>>>(pos, cov, col, opa, cm, g0, g1, g2, g3);
    gs_raster_tile<<<256, 1024, 0, stream>>>(g0, g1, g2, g3, (float*)d_out);
}

// Round 14
// 13.231 us; speedup vs baseline: 5.4389x; 1.0601x over previous
//
#include <hip/hip_runtime.h>
#include <math.h>

#define NG      1024
#define IMG_H   128
#define IMG_W   128
#define NPIX    (IMG_H * IMG_W)
#define MIN_A   (1.0f / 255.0f)
#define LOG2E   1.4426950408889634f

// Record layout (per gaussian, sorted by z):
//  g0 = {mx, my, a2, b2}          a2 = -0.5*conicA*log2e, b2 = -conicB*log2e
//  g1 = {c2, op_eff, colR, colG}  c2 = -0.5*conicC*log2e
//  g2 = colB
//  g3 = {mx, my, dxm, dym}        exact AABB of the alpha>=1/255 level set
// G = exp2( min(a2*dx^2 + c2*dy^2 + b2*dx*dy, 0) )

// ---------------------------------------------------------------------------
// Kernel 1: fused project + stable rank-sort + scatter. 64 blocks x 1024.
// Block owns 16 gaussians. z one-per-thread from direct coalesced pos loads
// (no staging phase); rank distributed 64-way (thread (g=tid&15, q=tid>>4)
// counts z-chunk [16q,16q+16) = 4 b128 reads); threads 0..15 sum partials,
// project their gaussian from direct global loads (contiguous 36B cov reads,
// latency hidden by 16-way TLP across blocks), scatter by rank.
// ---------------------------------------------------------------------------
__global__ __launch_bounds__(1024) void gs_prep(
    const float* __restrict__ pos, const float* __restrict__ cov,
    const float* __restrict__ col, const float* __restrict__ opa,
    const float* __restrict__ cm,
    float4* __restrict__ g0, float4* __restrict__ g1, float* __restrict__ g2,
    float4* __restrict__ g3)
{
    __shared__ float zsh[NG];            // 4 KB
    __shared__ int   prank[64][16];      // 4 KB [q][g]

    const int tid = threadIdx.x;
    const int b   = blockIdx.x;          // 64 blocks, 16 gaussians each

    // ---- z for gaussian `tid` from own coalesced pos load -----------------
    const float R20 = cm[8], R21 = cm[9], R22 = cm[10], T2 = cm[11];
    {
        const float p0 = pos[3*tid], p1 = pos[3*tid+1], p2 = pos[3*tid+2];
        zsh[tid] = fmaf(R20, p0, fmaf(R21, p1, fmaf(R22, p2, T2)));
    }
    __syncthreads();

    // ---- distributed stable rank (64-way: 4 b128 reads per thread) --------
    {
        const int g = tid & 15, q = tid >> 4;
        const int i = (b << 4) + g;
        const float zi = zsh[i];
        const float4* z4 = (const float4*)zsh;
        int r = 0;
        #pragma unroll
        for (int j4 = q * 4; j4 < q * 4 + 4; ++j4) {
            const float4 v = z4[j4];
            const int j = 4 * j4;
            r += (v.x < zi || (v.x == zi && j + 0 < i)) ? 1 : 0;
            r += (v.y < zi || (v.y == zi && j + 1 < i)) ? 1 : 0;
            r += (v.z < zi || (v.z == zi && j + 2 < i)) ? 1 : 0;
            r += (v.w < zi || (v.w == zi && j + 3 < i)) ? 1 : 0;
        }
        prank[q][g] = r;
    }
    __syncthreads();

    // ---- threads 0..15: sum rank, project, scatter ------------------------
    if (tid < 16) {
        const int g = tid;
        const int i = (b << 4) + g;

        int rank = 0;
        #pragma unroll
        for (int q = 0; q < 64; ++q) rank += prank[q][g];

        const float R00 = cm[0], R01 = cm[1], R02 = cm[2],  T0 = cm[3];
        const float R10 = cm[4], R11 = cm[5], R12 = cm[6],  T1 = cm[7];

        const float p0 = pos[3*i], p1 = pos[3*i+1], p2 = pos[3*i+2];
        const float x = R00*p0 + R01*p1 + R02*p2 + T0;
        const float y = R10*p0 + R11*p1 + R12*p2 + T1;
        const float z = zsh[i];

        const float focal = 110.85125168440814f;   // 0.5*128/tan(pi/6)
        const float zc = fmaxf(z, 1e-6f);
        const float mx = focal * x / zc + 0.5f * IMG_W;
        const float my = focal * y / zc + 0.5f * IMG_H;

        const float c00 = cov[9*i+0], c01 = cov[9*i+1], c02 = cov[9*i+2];
        const float c10 = cov[9*i+3], c11 = cov[9*i+4], c12 = cov[9*i+5];
        const float c20 = cov[9*i+6], c21 = cov[9*i+7], c22 = cov[9*i+8];
        const float s00 = c00, s01 = 0.5f*(c01+c10), s02 = 0.5f*(c02+c20);
        const float s11 = c11, s12 = 0.5f*(c12+c21), s22 = c22;

        const float RS00 = R00*s00 + R01*s01 + R02*s02;
        const float RS01 = R00*s01 + R01*s11 + R02*s12;
        const float RS02 = R00*s02 + R01*s12 + R02*s22;
        const float RS10 = R10*s00 + R11*s01 + R12*s02;
        const float RS11 = R10*s01 + R11*s11 + R12*s12;
        const float RS12 = R10*s02 + R11*s12 + R12*s22;
        const float RS20 = R20*s00 + R21*s01 + R22*s02;
        const float RS21 = R20*s01 + R21*s11 + R22*s12;
        const float RS22 = R20*s02 + R21*s12 + R22*s22;
        const float CC00 = RS00*R00 + RS01*R01 + RS02*R02;
        const float CC01 = RS00*R10 + RS01*R11 + RS02*R12;
        const float CC02 = RS00*R20 + RS01*R21 + RS02*R22;
        const float CC11 = RS10*R10 + RS11*R11 + RS12*R12;
        const float CC12 = RS10*R20 + RS11*R21 + RS12*R22;
        const float CC20 = RS20*R00 + RS21*R01 + RS22*R02;
        const float CC21 = RS20*R10 + RS21*R11 + RS22*R12;
        const float CC22 = RS20*R20 + RS21*R21 + RS22*R22;

        const float j00 = focal / zc, j02 = -focal * x / (zc*zc);
        const float j11 = focal / zc, j12 = -focal * y / (zc*zc);

        const float v00 = CC00*j00 + CC02*j02;
        const float v02 = CC20*j00 + CC22*j02;
        const float v10 = CC01*j11 + CC02*j12;
        const float v11 = CC11*j11 + CC12*j12;
        const float v12 = CC21*j11 + CC22*j12;

        const float a  = j00*v00 + j02*v02 + 0.3f;
        const float bq = j00*v10 + j02*v12;
        const float cQ = j11*v11 + j12*v12 + 0.3f;

        const float det = a*cQ - bq*bq;
        const float det_safe = (det > 0.f) ? det : 1.f;
        const float conA =  cQ / det_safe;
        const float conB = -bq / det_safe;
        const float conC =  a  / det_safe;

        const bool  valid  = (z > 0.2f) && (det > 0.f);
        const float op_eff = valid ? opa[i] : 0.f;

        float dxm, dym;
        if (op_eff * 255.f > 1.f) {
            const float sN = logf(255.f * op_eff);
            dxm = sqrtf(2.f * sN * a)  * 1.001f + 0.06f;   // conservative outward
            dym = sqrtf(2.f * sN * cQ) * 1.001f + 0.06f;
        } else {
            dxm = -1e30f; dym = -1e30f;                    // never visible
        }

        g0[rank] = make_float4(mx, my, -0.5f*conA*LOG2E, -conB*LOG2E);
        g1[rank] = make_float4(-0.5f*conC*LOG2E, op_eff, col[3*i], col[3*i+1]);
        g2[rank] = col[3*i+2];
        g3[rank] = make_float4(mx, my, dxm, dym);
    }
}

// ---------------------------------------------------------------------------
// Kernel 2 (unchanged from r13): LDS-resident tile raster, register-cull,
// fused combine. 256 blocks x 1024 threads, 1 block/CU.
// ---------------------------------------------------------------------------
__global__ __launch_bounds__(1024) void gs_raster_tile(
    const float4* __restrict__ g0, const float4* __restrict__ g1,
    const float*  __restrict__ g2, const float4* __restrict__ g3,
    float* __restrict__ out)
{
    __shared__ float4 s0[NG];            // 16 KB
    __shared__ float4 s1[NG];            // 16 KB
    __shared__ float  s2[NG];            //  4 KB
    __shared__ float4 part[16][64];      //  4 KB [chunk][pixel]

    const int tid = threadIdx.x;
    const float4 cl = g3[tid];           // coalesced; wave w lane l = gaussian 64w+l
    s0[tid] = g0[tid];
    s1[tid] = g1[tid];
    s2[tid] = g2[tid];

    const int w    = tid >> 6;           // wave = chunk 0..15
    const int lane = tid & 63;           // pixel in 8x8 tile / cull lane
    const int tile = blockIdx.x;         // 16x16 tiles
    const float tx0 = (float)((tile & 15) << 3);
    const float ty0 = (float)((tile >> 4) << 3);

    const float pxf = tx0 + (float)(lane & 7) + 0.5f;
    const float pyf = ty0 + (float)(lane >> 3) + 0.5f;
    const float txl = tx0 + 0.5f, txh = tx0 + 7.5f;
    const float tyl = ty0 + 0.5f, tyh = ty0 + 7.5f;

    // register cull -> uniform 64-bit mask (no LDS dependency)
    const bool hit = (cl.x - cl.z <= txh) && (cl.x + cl.z >= txl)
                  && (cl.y - cl.w <= tyh) && (cl.y + cl.w >= tyl);
    unsigned long long m = __ballot(hit);

    __syncthreads();                     // s0/s1/s2 ready

    const int base = w * 64;
    float T = 1.f, cr = 0.f, cg = 0.f, cb = 0.f;

    while (m) {                          // ascending bit order == z order
        const int i = __builtin_ctzll(m);
        m &= m - 1;
        const float4 A = s0[base + i];   // wave-uniform broadcasts
        const float4 B = s1[base + i];
        const float  C = s2[base + i];
        const float dx = pxf - A.x;
        const float dy = pyf - A.y;
        const float pw = fminf(A.z*dx*dx + B.x*dy*dy + A.w*(dx*dy), 0.f);
        const float G = __builtin_amdgcn_exp2f(pw);
        float alpha = fminf(B.y * G, 0.99f);
        alpha = (alpha >= MIN_A) ? alpha : 0.f;
        const float wT = alpha * T;
        cr = fmaf(wT, B.z, cr);
        cg = fmaf(wT, B.w, cg);
        cb = fmaf(wT, C,   cb);
        T *= (1.f - alpha);
    }

    part[w][lane] = make_float4(cr, cg, cb, T);
    __syncthreads();

    if (tid < 64) {                      // one thread per pixel: 16-chunk scan
        float Ts = 1.f, r = 0.f, g = 0.f, b = 0.f;
        #pragma unroll
        for (int k = 0; k < 16; ++k) {
            const float4 v = part[k][tid];
            r = fmaf(Ts, v.x, r);
            g = fmaf(Ts, v.y, g);
            b = fmaf(Ts, v.z, b);
            Ts *= v.w;
        }
        const int px = (int)tx0 + (tid & 7);
        const int py = (int)ty0 + (tid >> 3);
        float* o = out + 3 * (py * IMG_W + px);
        o[0] = r; o[1] = g; o[2] = b;
    }
}

// ---------------------------------------------------------------------------
extern "C" void kernel_launch(void* const* d_in, const int* in_sizes, int n_in,
                              void* d_out, int out_size, void* d_ws, size_t ws_size,
                              hipStream_t stream) {
    const float* pos = (const float*)d_in[0];
    const float* cov = (const float*)d_in[1];
    const float* col = (const float*)d_in[2];
    const float* opa = (const float*)d_in[3];
    const float* cm  = (const float*)d_in[4];

    char* ws = (char*)d_ws;
    float4* g0 = (float4*)(ws);                 // 16384 B
    float4* g1 = (float4*)(ws + 16384);         // 16384 B
    float*  g2 = (float*) (ws + 32768);         //  4096 B
    float4* g3 = (float4*)(ws + 36864);         // 16384 B

    gs_prep<<<64, 1024, 0, stream>>>(pos, cov, col, opa, cm, g0, g1, g2, g3);
    gs_raster_tile<<<256, 1024, 0, stream>>>(g0, g1, g2, g3, (float*)d_out);
}